// Round 2
// baseline (1422.669 us; speedup 1.0000x reference)
//
#include <hip/hip_runtime.h>

#define H 20

__device__ __forceinline__ float fsigmoid(float x) {
    return 1.0f / (1.0f + __expf(-x));
}
__device__ __forceinline__ float ftanh(float x) {
    float e = __expf(2.0f * x);
    return 1.0f - 2.0f / (e + 1.0f);
}

// One LSTM cell step for a single batch element held in registers.
// Fully unrolled: weight indices are compile-time constants -> wave-uniform
// addresses -> scalar (s_load) weight fetches riding the SMEM pipe.
template <int IN>
__device__ __forceinline__ void cell(const float* __restrict__ Wih,
                                     const float* __restrict__ Whh,
                                     const float* __restrict__ bias,
                                     const float (&x)[IN],
                                     float (&h)[H], float (&c)[H]) {
    float hn[H];
#pragma unroll
    for (int u = 0; u < H; ++u) {
        float gi = bias[u];
        float gf = bias[H + u];
        float gg = bias[2 * H + u];
        float go = bias[3 * H + u];
#pragma unroll
        for (int k = 0; k < IN; ++k) {
            float xk = x[k];
            gi = fmaf(Wih[u * IN + k],           xk, gi);
            gf = fmaf(Wih[(H + u) * IN + k],     xk, gf);
            gg = fmaf(Wih[(2 * H + u) * IN + k], xk, gg);
            go = fmaf(Wih[(3 * H + u) * IN + k], xk, go);
        }
#pragma unroll
        for (int k = 0; k < H; ++k) {
            float hk = h[k];
            gi = fmaf(Whh[u * H + k],           hk, gi);
            gf = fmaf(Whh[(H + u) * H + k],     hk, gf);
            gg = fmaf(Whh[(2 * H + u) * H + k], hk, gg);
            go = fmaf(Whh[(3 * H + u) * H + k], hk, go);
        }
        float cn = fsigmoid(gf) * c[u] + fsigmoid(gi) * ftanh(gg);
        c[u] = cn;
        hn[u] = fsigmoid(go) * ftanh(cn);
    }
#pragma unroll
    for (int u = 0; u < H; ++u) h[u] = hn[u];
}

// No __launch_bounds__: R1 showed (256,2) made the allocator hold state in
// scratch (VGPR=96, 444MB extra HBM fetch). State needs ~140-170 VGPRs ->
// still 3 waves/SIMD from the ~512-VGPR pool.
__global__ void lstm_ar_kernel(
    const float* __restrict__ y_past, const float* __restrict__ x_past,
    const float* __restrict__ u_past, const float* __restrict__ s_past,
    const float* __restrict__ u_future,
    const float* __restrict__ Wih1_0, const float* __restrict__ Whh1_0, const float* __restrict__ b1_0,
    const float* __restrict__ Wih1_1, const float* __restrict__ Whh1_1, const float* __restrict__ b1_1,
    const float* __restrict__ Wih2_0, const float* __restrict__ Whh2_0, const float* __restrict__ b2_0,
    const float* __restrict__ Wih2_1, const float* __restrict__ Whh2_1, const float* __restrict__ b2_1,
    const float* __restrict__ fW1, const float* __restrict__ fb1,
    const float* __restrict__ fW2, const float* __restrict__ fb2,
    const float* __restrict__ fW3, const float* __restrict__ fb3,
    float* __restrict__ out, int B) {
    int b = blockIdx.x * blockDim.x + threadIdx.x;
    if (b >= B) return;

    float h0[H], c0[H], h1[H], c1[H];
#pragma unroll
    for (int u = 0; u < H; ++u) { h0[u] = 0.f; c0[u] = 0.f; h1[u] = 0.f; c1[u] = 0.f; }

    // ---- encoder over lookback T=8 (input = concat[y,x,u,s] = 16 feats) ----
    for (int t = 0; t < 8; ++t) {
        float x[16];
        x[0] = y_past[b * 8 + t];
        {   // x_past row: 8 contiguous floats -> two float4 loads
            const float4* p = (const float4*)(x_past + (size_t)(b * 8 + t) * 8);
            float4 a0 = p[0], a1 = p[1];
            x[1] = a0.x; x[2] = a0.y; x[3] = a0.z; x[4] = a0.w;
            x[5] = a1.x; x[6] = a1.y; x[7] = a1.z; x[8] = a1.w;
        }
        {   // u_past row: 4 contiguous floats
            const float4* p = (const float4*)(u_past + (size_t)(b * 8 + t) * 4);
            float4 a0 = p[0];
            x[9] = a0.x; x[10] = a0.y; x[11] = a0.z; x[12] = a0.w;
        }
        {   // s_past row: 3 floats (not 16B aligned; float2+float)
            const float* p = s_past + (size_t)(b * 8 + t) * 3;
            x[13] = p[0]; x[14] = p[1]; x[15] = p[2];
        }
        cell<16>(Wih1_0, Whh1_0, b1_0, x, h0, c0);
        cell<H>(Wih1_1, Whh1_1, b1_1, h0, h1, c1);
    }

    // ---- decoder over lookahead T=4 (input = u_future, 4 feats) + MLP head ----
    for (int t = 0; t < 4; ++t) {
        float x[4];
        {
            const float4* p = (const float4*)(u_future + (size_t)(b * 4 + t) * 4);
            float4 a0 = p[0];
            x[0] = a0.x; x[1] = a0.y; x[2] = a0.z; x[3] = a0.w;
        }
        cell<4>(Wih2_0, Whh2_0, b2_0, x, h0, c0);
        cell<H>(Wih2_1, Whh2_1, b2_1, h0, h1, c1);

        // FCNN 20 -> 10 -> 10 -> 1
        float z1[10];
#pragma unroll
        for (int j = 0; j < 10; ++j) {
            float a = fb1[j];
#pragma unroll
            for (int k = 0; k < H; ++k) a = fmaf(fW1[j * H + k], h1[k], a);
            z1[j] = fmaxf(a, 0.f);
        }
        float z2[10];
#pragma unroll
        for (int j = 0; j < 10; ++j) {
            float a = fb2[j];
#pragma unroll
            for (int k = 0; k < 10; ++k) a = fmaf(fW2[j * 10 + k], z1[k], a);
            z2[j] = fmaxf(a, 0.f);
        }
        float o = fb3[0];
#pragma unroll
        for (int k = 0; k < 10; ++k) o = fmaf(fW3[k], z2[k], o);
        out[b * 4 + t] = o;
    }
}

extern "C" void kernel_launch(void* const* d_in, const int* in_sizes, int n_in,
                              void* d_out, int out_size, void* d_ws, size_t ws_size,
                              hipStream_t stream) {
    (void)n_in; (void)d_ws; (void)ws_size;
    const float* y_past   = (const float*)d_in[0];
    const float* x_past   = (const float*)d_in[1];
    const float* u_past   = (const float*)d_in[2];
    const float* s_past   = (const float*)d_in[3];
    const float* u_future = (const float*)d_in[4];
    const float* Wih1_0 = (const float*)d_in[5];
    const float* Whh1_0 = (const float*)d_in[6];
    const float* b1_0   = (const float*)d_in[7];
    const float* Wih1_1 = (const float*)d_in[8];
    const float* Whh1_1 = (const float*)d_in[9];
    const float* b1_1   = (const float*)d_in[10];
    const float* Wih2_0 = (const float*)d_in[11];
    const float* Whh2_0 = (const float*)d_in[12];
    const float* b2_0   = (const float*)d_in[13];
    const float* Wih2_1 = (const float*)d_in[14];
    const float* Whh2_1 = (const float*)d_in[15];
    const float* b2_1   = (const float*)d_in[16];
    const float* fW1 = (const float*)d_in[17];
    const float* fb1 = (const float*)d_in[18];
    const float* fW2 = (const float*)d_in[19];
    const float* fb2 = (const float*)d_in[20];
    const float* fW3 = (const float*)d_in[21];
    const float* fb3 = (const float*)d_in[22];
    float* out = (float*)d_out;

    int B = in_sizes[0] / 8;  // y_past is [B,8,1]
    (void)out_size;

    dim3 block(256);
    dim3 grid((B + 255) / 256);
    lstm_ar_kernel<<<grid, block, 0, stream>>>(
        y_past, x_past, u_past, s_past, u_future,
        Wih1_0, Whh1_0, b1_0, Wih1_1, Whh1_1, b1_1,
        Wih2_0, Whh2_0, b2_0, Wih2_1, Whh2_1, b2_1,
        fW1, fb1, fW2, fb2, fW3, fb3, out, B);
}

// Round 3
// 1229.596 us; speedup vs baseline: 1.1570x; 1.1570x over previous
//
#include <hip/hip_runtime.h>

#define H 20

// Raw v_rcp_f32 (~1 ulp) instead of IEEE division: strict fp32 div expands to
// ~9 insts (div_scale/div_fmas/div_fixup); 2400 divides/thread was ~20% of
// total VALU work. Accuracy impact ~1e-7 rel, threshold is 1.9e-3.
__device__ __forceinline__ float fast_rcp(float x) { return __builtin_amdgcn_rcpf(x); }

__device__ __forceinline__ float fsigmoid(float x) {
    return fast_rcp(1.0f + __expf(-x));   // saturation-safe
}
__device__ __forceinline__ float ftanh(float x) {
    float e = __expf(2.0f * x);           // saturation-safe
    return 1.0f - 2.0f * fast_rcp(e + 1.0f);
}

// One LSTM cell step for a single batch element held in registers.
// Fully unrolled: weight indices are compile-time constants -> wave-uniform
// addresses -> scalar (s_load) weight fetches riding the SMEM pipe.
template <int IN>
__device__ __forceinline__ void cell(const float* __restrict__ Wih,
                                     const float* __restrict__ Whh,
                                     const float* __restrict__ bias,
                                     const float (&x)[IN],
                                     float (&h)[H], float (&c)[H]) {
    float hn[H];
#pragma unroll
    for (int u = 0; u < H; ++u) {
        float gi = bias[u];
        float gf = bias[H + u];
        float gg = bias[2 * H + u];
        float go = bias[3 * H + u];
#pragma unroll
        for (int k = 0; k < IN; ++k) {
            float xk = x[k];
            gi = fmaf(Wih[u * IN + k],           xk, gi);
            gf = fmaf(Wih[(H + u) * IN + k],     xk, gf);
            gg = fmaf(Wih[(2 * H + u) * IN + k], xk, gg);
            go = fmaf(Wih[(3 * H + u) * IN + k], xk, go);
        }
#pragma unroll
        for (int k = 0; k < H; ++k) {
            float hk = h[k];
            gi = fmaf(Whh[u * H + k],           hk, gi);
            gf = fmaf(Whh[(H + u) * H + k],     hk, gf);
            gg = fmaf(Whh[(2 * H + u) * H + k], hk, gg);
            go = fmaf(Whh[(3 * H + u) * H + k], hk, go);
        }
        float cn = fsigmoid(gf) * c[u] + fsigmoid(gi) * ftanh(gg);
        c[u] = cn;
        hn[u] = fsigmoid(go) * ftanh(cn);
    }
#pragma unroll
    for (int u = 0; u < H; ++u) h[u] = hn[u];
}

// waves_per_eu(2,2): R1/R2 showed the pre-RA scheduler targets high occupancy
// (VGPR=64..96) and spills the long-lived h/c state to scratch (500+ MB HBM
// re-reads). Pinning min=max=2 waves/EU fixes the pressure target at 256
// VGPRs; peak live state is ~180, so spills should vanish.
__attribute__((amdgpu_waves_per_eu(2, 2)))
__global__ void __launch_bounds__(256) lstm_ar_kernel(
    const float* __restrict__ y_past, const float* __restrict__ x_past,
    const float* __restrict__ u_past, const float* __restrict__ s_past,
    const float* __restrict__ u_future,
    const float* __restrict__ Wih1_0, const float* __restrict__ Whh1_0, const float* __restrict__ b1_0,
    const float* __restrict__ Wih1_1, const float* __restrict__ Whh1_1, const float* __restrict__ b1_1,
    const float* __restrict__ Wih2_0, const float* __restrict__ Whh2_0, const float* __restrict__ b2_0,
    const float* __restrict__ Wih2_1, const float* __restrict__ Whh2_1, const float* __restrict__ b2_1,
    const float* __restrict__ fW1, const float* __restrict__ fb1,
    const float* __restrict__ fW2, const float* __restrict__ fb2,
    const float* __restrict__ fW3, const float* __restrict__ fb3,
    float* __restrict__ out, int B) {
    int b = blockIdx.x * blockDim.x + threadIdx.x;
    if (b >= B) return;

    float h0[H], c0[H], h1[H], c1[H];
#pragma unroll
    for (int u = 0; u < H; ++u) { h0[u] = 0.f; c0[u] = 0.f; h1[u] = 0.f; c1[u] = 0.f; }

    // ---- encoder over lookback T=8 (input = concat[y,x,u,s] = 16 feats) ----
    for (int t = 0; t < 8; ++t) {
        float x[16];
        x[0] = y_past[b * 8 + t];
        {   // x_past row: 8 contiguous floats -> two float4 loads
            const float4* p = (const float4*)(x_past + (size_t)(b * 8 + t) * 8);
            float4 a0 = p[0], a1 = p[1];
            x[1] = a0.x; x[2] = a0.y; x[3] = a0.z; x[4] = a0.w;
            x[5] = a1.x; x[6] = a1.y; x[7] = a1.z; x[8] = a1.w;
        }
        {   // u_past row: 4 contiguous floats
            const float4* p = (const float4*)(u_past + (size_t)(b * 8 + t) * 4);
            float4 a0 = p[0];
            x[9] = a0.x; x[10] = a0.y; x[11] = a0.z; x[12] = a0.w;
        }
        {   // s_past row: 3 floats
            const float* p = s_past + (size_t)(b * 8 + t) * 3;
            x[13] = p[0]; x[14] = p[1]; x[15] = p[2];
        }
        cell<16>(Wih1_0, Whh1_0, b1_0, x, h0, c0);
        cell<H>(Wih1_1, Whh1_1, b1_1, h0, h1, c1);
    }

    // ---- decoder over lookahead T=4 (input = u_future, 4 feats) + MLP head ----
    for (int t = 0; t < 4; ++t) {
        float x[4];
        {
            const float4* p = (const float4*)(u_future + (size_t)(b * 4 + t) * 4);
            float4 a0 = p[0];
            x[0] = a0.x; x[1] = a0.y; x[2] = a0.z; x[3] = a0.w;
        }
        cell<4>(Wih2_0, Whh2_0, b2_0, x, h0, c0);
        cell<H>(Wih2_1, Whh2_1, b2_1, h0, h1, c1);

        // FCNN 20 -> 10 -> 10 -> 1
        float z1[10];
#pragma unroll
        for (int j = 0; j < 10; ++j) {
            float a = fb1[j];
#pragma unroll
            for (int k = 0; k < H; ++k) a = fmaf(fW1[j * H + k], h1[k], a);
            z1[j] = fmaxf(a, 0.f);
        }
        float z2[10];
#pragma unroll
        for (int j = 0; j < 10; ++j) {
            float a = fb2[j];
#pragma unroll
            for (int k = 0; k < 10; ++k) a = fmaf(fW2[j * 10 + k], z1[k], a);
            z2[j] = fmaxf(a, 0.f);
        }
        float o = fb3[0];
#pragma unroll
        for (int k = 0; k < 10; ++k) o = fmaf(fW3[k], z2[k], o);
        out[b * 4 + t] = o;
    }
}

extern "C" void kernel_launch(void* const* d_in, const int* in_sizes, int n_in,
                              void* d_out, int out_size, void* d_ws, size_t ws_size,
                              hipStream_t stream) {
    (void)n_in; (void)d_ws; (void)ws_size;
    const float* y_past   = (const float*)d_in[0];
    const float* x_past   = (const float*)d_in[1];
    const float* u_past   = (const float*)d_in[2];
    const float* s_past   = (const float*)d_in[3];
    const float* u_future = (const float*)d_in[4];
    const float* Wih1_0 = (const float*)d_in[5];
    const float* Whh1_0 = (const float*)d_in[6];
    const float* b1_0   = (const float*)d_in[7];
    const float* Wih1_1 = (const float*)d_in[8];
    const float* Whh1_1 = (const float*)d_in[9];
    const float* b1_1   = (const float*)d_in[10];
    const float* Wih2_0 = (const float*)d_in[11];
    const float* Whh2_0 = (const float*)d_in[12];
    const float* b2_0   = (const float*)d_in[13];
    const float* Wih2_1 = (const float*)d_in[14];
    const float* Whh2_1 = (const float*)d_in[15];
    const float* b2_1   = (const float*)d_in[16];
    const float* fW1 = (const float*)d_in[17];
    const float* fb1 = (const float*)d_in[18];
    const float* fW2 = (const float*)d_in[19];
    const float* fb2 = (const float*)d_in[20];
    const float* fW3 = (const float*)d_in[21];
    const float* fb3 = (const float*)d_in[22];
    float* out = (float*)d_out;

    int B = in_sizes[0] / 8;  // y_past is [B,8,1]
    (void)out_size;

    dim3 block(256);
    dim3 grid((B + 255) / 256);
    lstm_ar_kernel<<<grid, block, 0, stream>>>(
        y_past, x_past, u_past, s_past, u_future,
        Wih1_0, Whh1_0, b1_0, Wih1_1, Whh1_1, b1_1,
        Wih2_0, Whh2_0, b2_0, Wih2_1, Whh2_1, b2_1,
        fW1, fb1, fW2, fb2, fW3, fb3, out, B);
}